// Round 3
// baseline (1136.134 us; speedup 1.0000x reference)
//
#include <hip/hip_runtime.h>
#include <stdint.h>

#define DIM     1280
#define NHEADS  16
#define HD      80
#define NV      16
#define MAXP    1024
#define MTOT    (NV*MAXP)   // 16384

typedef __bf16 bf16;
using bf16x8 = __attribute__((ext_vector_type(8))) __bf16;
using f32x4  = __attribute__((ext_vector_type(4))) float;

// load 8 consecutive elements as bf16x8 (fp32 source: convert; bf16 source: raw)
template<typename T>
__device__ __forceinline__ bf16x8 load8_bf16(const T* p) {
    if constexpr (sizeof(T) == 4) {
        const float4 f0 = *(const float4*)(p);
        const float4 f1 = *(const float4*)(p + 4);
        bf16x8 r;
        r[0] = (bf16)f0.x; r[1] = (bf16)f0.y; r[2] = (bf16)f0.z; r[3] = (bf16)f0.w;
        r[4] = (bf16)f1.x; r[5] = (bf16)f1.y; r[6] = (bf16)f1.z; r[7] = (bf16)f1.w;
        return r;
    } else {
        return *(const bf16x8*)p;
    }
}

// ---------------------------------------------------------------------------
// NT GEMM: C[M x N] = A[M x K] * B[N x K]^T + bias, K = 1280, fp32/bf16 in,
// bf16 MFMA, fp32 acc. BM=BN=64, BK=64; 256 threads = 4 waves, wave = 32x32.
// IS_QKV: scatter into q [n][h][p][80], k [n][h][p][80], v^T [n][h][80][p] (bf16).
// else  : fp32 row-major [M][DIM] output (the proj GEMM).
// ---------------------------------------------------------------------------
template<typename TA, typename TB, bool IS_QKV>
__global__ __launch_bounds__(256)
void gemm_nt(const TA* __restrict__ A, const TB* __restrict__ B,
             const float* __restrict__ bias,
             bf16* __restrict__ out0, bf16* __restrict__ out1,
             bf16* __restrict__ out2, float* __restrict__ outf)
{
    const int K = DIM;
    __shared__ __align__(16) bf16 As[64*72];   // row stride 72 bf16 = 144 B
    __shared__ __align__(16) bf16 Bs[64*72];

    const int tid  = threadIdx.x;
    const int lane = tid & 63, wave = tid >> 6;
    const int quad = lane >> 4, c16 = lane & 15;
    const int wm = wave & 1, wn = wave >> 1;
    const int mb = blockIdx.y, nb = blockIdx.x;
    const long a_base = (long)mb * 64 * K;
    const long b_base = (long)nb * 64 * K;

    f32x4 acc[2][2] = {};

    for (int kt = 0; kt < K/64; ++kt) {
        __syncthreads();
        #pragma unroll
        for (int i = 0; i < 2; ++i) {
            int idx = i*256 + tid;
            int row = idx >> 3, c = idx & 7;
            *(bf16x8*)(As + row*72 + c*8) =
                load8_bf16(A + a_base + (long)row*K + kt*64 + c*8);
        }
        #pragma unroll
        for (int i = 0; i < 2; ++i) {
            int idx = i*256 + tid;
            int row = idx >> 3, c = idx & 7;
            *(bf16x8*)(Bs + row*72 + c*8) =
                load8_bf16(B + b_base + (long)row*K + kt*64 + c*8);
        }
        __syncthreads();
        #pragma unroll
        for (int kk = 0; kk < 2; ++kk) {
            const int ko = kk*32 + quad*8;
            bf16x8 a0 = *(const bf16x8*)(As + (wm*32 +      c16)*72 + ko);
            bf16x8 a1 = *(const bf16x8*)(As + (wm*32 + 16 + c16)*72 + ko);
            bf16x8 b0 = *(const bf16x8*)(Bs + (wn*32 +      c16)*72 + ko);
            bf16x8 b1 = *(const bf16x8*)(Bs + (wn*32 + 16 + c16)*72 + ko);
            acc[0][0] = __builtin_amdgcn_mfma_f32_16x16x32_bf16(a0, b0, acc[0][0], 0,0,0);
            acc[0][1] = __builtin_amdgcn_mfma_f32_16x16x32_bf16(a0, b1, acc[0][1], 0,0,0);
            acc[1][0] = __builtin_amdgcn_mfma_f32_16x16x32_bf16(a1, b0, acc[1][0], 0,0,0);
            acc[1][1] = __builtin_amdgcn_mfma_f32_16x16x32_bf16(a1, b1, acc[1][1], 0,0,0);
        }
    }

    // epilogue: C/D layout col = c16 (+tile), row = quad*4 + r (+tile)
    #pragma unroll
    for (int mt = 0; mt < 2; ++mt) {
        #pragma unroll
        for (int nt = 0; nt < 2; ++nt) {
            const int col = nb*64 + wn*32 + nt*16 + c16;
            const float bv = bias[col];
            if constexpr (IS_QKV) {
                const int which = (col >= 2*DIM) ? 2 : (col >= DIM ? 1 : 0);
                const int rr = col - which*DIM;
                const int h  = rr / HD;
                const int d  = rr - h*HD;
                #pragma unroll
                for (int r = 0; r < 4; ++r) {
                    const int row = mb*64 + wm*32 + mt*16 + quad*4 + r;
                    const int n = row >> 10, p = row & 1023;
                    const bf16 bf = (bf16)(acc[mt][nt][r] + bv);
                    if (which == 2) {
                        out2[((long)((n*NHEADS + h)*HD + d))*MAXP + p] = bf;   // v^T [n][h][d][p]
                    } else {
                        bf16* dst = which ? out1 : out0;                       // q/k [n][h][p][80]
                        dst[((long)((n*NHEADS + h)*MAXP + p))*HD + d] = bf;
                    }
                }
            } else {
                #pragma unroll
                for (int r = 0; r < 4; ++r) {
                    const int row = mb*64 + wm*32 + mt*16 + quad*4 + r;
                    outf[(long)row*DIM + col] = acc[mt][nt][r] + bv;
                }
            }
        }
    }
}

// ---------------------------------------------------------------------------
// RoPE in-place on q,k (bf16 [n][h][p][80]); rope cache fp32 [n][p][160]
// (80 cos then 80 sin). One thread per (array, n, h, p, d<40) handles the
// (d, d+40) pair. 1/sqrt(80) folded into q.
// ---------------------------------------------------------------------------
__global__ __launch_bounds__(256)
void rope_kernel(bf16* __restrict__ qb, bf16* __restrict__ kb,
                 const float* __restrict__ rope)
{
    const int t = blockIdx.x * 256 + threadIdx.x;  // 2*16*16*1024*40 = 20971520
    const int d = t % 40;
    const int rest = t / 40;
    const int p = rest & 1023;
    const int r2 = rest >> 10;
    const int h = r2 & 15;
    const int r3 = r2 >> 4;
    const int n = r3 & 15;
    const int a = r3 >> 4;                          // 0 = q, 1 = k (block-uniform)
    bf16* arr = a ? kb : qb;
    const long base = ((long)((n*NHEADS + h)*MAXP + p))*HD;
    const float* rc = rope + ((long)(n*MAXP + p))*160;
    const float x1 = (float)arr[base + d];
    const float x2 = (float)arr[base + d + 40];
    float o1 = x1 * rc[d]      - x2 * rc[80 + d];        // cos[d],    sin[d]
    float o2 = x2 * rc[40 + d] + x1 * rc[120 + d];       // cos[d+40], sin[d+40]
    if (a == 0) { o1 *= 0.11180339887498949f; o2 *= 0.11180339887498949f; }
    arr[base + d]      = (bf16)o1;
    arr[base + d + 40] = (bf16)o2;
}

// ---------------------------------------------------------------------------
// Flash attention. Block = (q-tile of 64, h, n); 4 waves x 16 q-rows.
// Q/K global layout [n][h][p][80] bf16; LDS tiles padded to 96 cols (zeroed).
// K-tiles of 64 keys; S = Q K^T via MFMA (3 K-steps), online softmax,
// P -> LDS (C-layout -> A-layout), PV via MFMA (V staged transposed).
// ---------------------------------------------------------------------------
__global__ __launch_bounds__(256)
void attn_kernel(const bf16* __restrict__ qb, const bf16* __restrict__ kb,
                 const bf16* __restrict__ vt, const int* __restrict__ seq_lens,
                 bf16* __restrict__ outb)
{
    __shared__ __align__(16) bf16 Qs[64*104];    // stride 104 bf16 = 208 B
    __shared__ __align__(16) bf16 Ks[64*104];
    __shared__ __align__(16) bf16 Vts[80*72];    // V^T: [d][key], stride 144 B
    __shared__ __align__(16) bf16 Ps[4][16*72];  // per-wave P tile

    const int tid  = threadIdx.x;
    const int lane = tid & 63, wave = tid >> 6;
    const int quad = lane >> 4, c16 = lane & 15;
    const int qt = blockIdx.x, h = blockIdx.y, n = blockIdx.z;
    const int seqlen = seq_lens[n];

    const long qkbase = ((long)(n*NHEADS + h)) * MAXP * HD;
    const long vbase  = ((long)(n*NHEADS + h)) * HD * MAXP;

    const float4 zero4 = make_float4(0.f, 0.f, 0.f, 0.f);

    for (int i = tid; i < 768; i += 256) {       // 64 rows x 12 chunks of 16B
        int row = i / 12, c = i % 12;
        float4 v = (c < 10)
            ? *(const float4*)(qb + qkbase + (long)(qt*64 + row)*HD + c*8)
            : zero4;
        *(float4*)(Qs + row*104 + c*8) = v;
    }
    __syncthreads();
    bf16x8 aq[3];
    #pragma unroll
    for (int kc = 0; kc < 3; ++kc)
        aq[kc] = *(const bf16x8*)(Qs + (wave*16 + c16)*104 + kc*32 + quad*8);

    float mrow[4], lrow[4];
    #pragma unroll
    for (int r = 0; r < 4; ++r) { mrow[r] = -1e30f; lrow[r] = 0.0f; }
    f32x4 O[5] = {};

    const int nkt = (seqlen + 63) >> 6;
    for (int kt = 0; kt < nkt; ++kt) {
        __syncthreads();
        for (int i = tid; i < 768; i += 256) {
            int row = i / 12, c = i % 12;
            float4 v = (c < 10)
                ? *(const float4*)(kb + qkbase + (long)(kt*64 + row)*HD + c*8)
                : zero4;
            *(float4*)(Ks + row*104 + c*8) = v;
        }
        for (int i = tid; i < 640; i += 256) {   // 80 d-rows x 8 chunks
            int d = i >> 3, c = i & 7;
            *(float4*)(Vts + d*72 + c*8) =
                *(const float4*)(vt + vbase + (long)d*MAXP + kt*64 + c*8);
        }
        __syncthreads();

        f32x4 S[4] = {};
        #pragma unroll
        for (int kc = 0; kc < 3; ++kc) {
            const int ko = kc*32 + quad*8;
            #pragma unroll
            for (int nt = 0; nt < 4; ++nt) {
                bf16x8 bk = *(const bf16x8*)(Ks + (nt*16 + c16)*104 + ko);
                S[nt] = __builtin_amdgcn_mfma_f32_16x16x32_bf16(aq[kc], bk, S[nt], 0,0,0);
            }
        }
        #pragma unroll
        for (int nt = 0; nt < 4; ++nt) {
            const int key = kt*64 + nt*16 + c16;
            if (key >= seqlen) {
                #pragma unroll
                for (int r = 0; r < 4; ++r) S[nt][r] = -1e30f;
            }
        }
        float alpha[4];
        #pragma unroll
        for (int r = 0; r < 4; ++r) {
            float rm = fmaxf(fmaxf(S[0][r], S[1][r]), fmaxf(S[2][r], S[3][r]));
            rm = fmaxf(rm, __shfl_xor(rm, 1, 16));
            rm = fmaxf(rm, __shfl_xor(rm, 2, 16));
            rm = fmaxf(rm, __shfl_xor(rm, 4, 16));
            rm = fmaxf(rm, __shfl_xor(rm, 8, 16));
            const float nm = fmaxf(mrow[r], rm);
            alpha[r] = __expf(mrow[r] - nm);
            mrow[r] = nm;
            float rs = 0.0f;
            #pragma unroll
            for (int nt = 0; nt < 4; ++nt) {
                const float pv = __expf(S[nt][r] - nm);
                S[nt][r] = pv;
                rs += pv;
            }
            rs += __shfl_xor(rs, 1, 16);
            rs += __shfl_xor(rs, 2, 16);
            rs += __shfl_xor(rs, 4, 16);
            rs += __shfl_xor(rs, 8, 16);
            lrow[r] = lrow[r]*alpha[r] + rs;
        }
        #pragma unroll
        for (int dt = 0; dt < 5; ++dt)
            #pragma unroll
            for (int r = 0; r < 4; ++r)
                O[dt][r] *= alpha[r];
        #pragma unroll
        for (int nt = 0; nt < 4; ++nt)
            #pragma unroll
            for (int r = 0; r < 4; ++r)
                Ps[wave][(quad*4 + r)*72 + nt*16 + c16] = (bf16)S[nt][r];
        __syncthreads();
        #pragma unroll
        for (int kc = 0; kc < 2; ++kc) {
            bf16x8 ap = *(const bf16x8*)(Ps[wave] + c16*72 + kc*32 + quad*8);
            #pragma unroll
            for (int dt = 0; dt < 5; ++dt) {
                bf16x8 bv = *(const bf16x8*)(Vts + (dt*16 + c16)*72 + kc*32 + quad*8);
                O[dt] = __builtin_amdgcn_mfma_f32_16x16x32_bf16(ap, bv, O[dt], 0,0,0);
            }
        }
    }

    #pragma unroll
    for (int dt = 0; dt < 5; ++dt) {
        #pragma unroll
        for (int r = 0; r < 4; ++r) {
            const int p = qt*64 + wave*16 + quad*4 + r;
            const float v = O[dt][r] / lrow[r];
            outb[((long)(n*MAXP + p))*DIM + h*HD + dt*16 + c16] = (bf16)v;
        }
    }
}

// ---------------------------------------------------------------------------
// Buffer plan (fp32 world):
//   q, k (bf16, 42 MB each) -> d_out (fp32, 84 MB); proj overwrites d_out last.
//   attn_o (bf16, 42 MB)    -> d_in[0] (hidden fully consumed by QKV GEMM
//                              first; harness restores inputs every launch).
//   v^T (bf16, 42 MB)       -> d_ws.
// ---------------------------------------------------------------------------
extern "C" void kernel_launch(void* const* d_in, const int* in_sizes, int n_in,
                              void* d_out, int out_size, void* d_ws, size_t ws_size,
                              hipStream_t stream)
{
    const float* hidden = (const float*)d_in[0];
    const float* rope   = (const float*)d_in[1];
    const int*   seql   = (const int*)d_in[2];
    const float* wqkv   = (const float*)d_in[3];
    const float* bqkv   = (const float*)d_in[4];
    const float* wproj  = (const float*)d_in[5];
    const float* bproj  = (const float*)d_in[6];
    float* out = (float*)d_out;

    const size_t QK_ELEMS = (size_t)NV*NHEADS*MAXP*HD;    // 20,971,520

    bf16* q_b = (bf16*)d_out;
    bf16* k_b = q_b + QK_ELEMS;        // second half of d_out
    bf16* v_t = (bf16*)d_ws;           // 42 MB of workspace
    bf16* a_b = (bf16*)d_in[0];        // attention output overwrites hidden

    gemm_nt<float, float, true><<<dim3(3*DIM/64, MTOT/64), 256, 0, stream>>>(
        hidden, wqkv, bqkv, q_b, k_b, v_t, nullptr);

    rope_kernel<<<(2*NV*NHEADS*MAXP*40)/256, 256, 0, stream>>>(q_b, k_b, rope);

    attn_kernel<<<dim3(MAXP/64, NHEADS, NV), 256, 0, stream>>>(
        q_b, k_b, v_t, seql, a_b);

    gemm_nt<bf16, float, false><<<dim3(DIM/64, MTOT/64), 256, 0, stream>>>(
        a_b, wproj, bproj, nullptr, nullptr, nullptr, out);
}

// Round 4
// 886.243 us; speedup vs baseline: 1.2820x; 1.2820x over previous
//
#include <hip/hip_runtime.h>
#include <stdint.h>

#define DIM     1280
#define NHEADS  16
#define HD      80
#define NV      16
#define MAXP    1024
#define MTOT    (NV*MAXP)   // 16384

typedef __bf16 bf16;
using bf16x8 = __attribute__((ext_vector_type(8))) __bf16;
using bf16x4 = __attribute__((ext_vector_type(4))) __bf16;
using f32x4  = __attribute__((ext_vector_type(4))) float;

#define GLOAD_LDS16(g, l)                                                     \
    __builtin_amdgcn_global_load_lds(                                         \
        (const __attribute__((address_space(1))) void*)(g),                   \
        (__attribute__((address_space(3))) void*)(l), 16, 0, 0)

// ---------------------------------------------------------------------------
// fp32 -> bf16 bulk convert (vectorized, n must be a multiple of 4)
// ---------------------------------------------------------------------------
__global__ __launch_bounds__(256)
void cvt_bf16(const float* __restrict__ src, bf16* __restrict__ dst, int n4)
{
    const int i = blockIdx.x * 256 + threadIdx.x;
    if (i < n4) {
        const float4 f = ((const float4*)src)[i];
        bf16x4 r;
        r[0] = (bf16)f.x; r[1] = (bf16)f.y; r[2] = (bf16)f.z; r[3] = (bf16)f.w;
        ((bf16x4*)dst)[i] = r;
    }
}

// ---------------------------------------------------------------------------
// m97-structure NT GEMM: C[M x N] = A[M x K] * B[N x K]^T + bias.
// A, B bf16 row-major (K contiguous), K = 1280. BM=BN=128, BK=64.
// 256 threads = 4 waves in 2x2; each wave computes 64x64 = 4x4 MFMA 16x16 tiles.
// Staging via global_load_lds width=16 into unpadded 128x64 LDS tiles.
// IS_QKV: scatter into q [n][h][p][80], k [n][h][p][80], v^T [n][h][80][p] (bf16).
// else  : fp32 row-major [M][DIM] output (proj).
// ---------------------------------------------------------------------------
template<bool IS_QKV>
__global__ __launch_bounds__(256)
void gemm_nt_big(const bf16* __restrict__ A, const bf16* __restrict__ B,
                 const float* __restrict__ bias,
                 bf16* __restrict__ out0, bf16* __restrict__ out1,
                 bf16* __restrict__ out2, float* __restrict__ outf)
{
    const int K = DIM;
    __shared__ __align__(16) bf16 As[128*64];   // unpadded: global_load_lds layout
    __shared__ __align__(16) bf16 Bs[128*64];

    const int tid  = threadIdx.x;
    const int lane = tid & 63, wave = tid >> 6;
    const int quad = lane >> 4, c16 = lane & 15;
    const int wm = wave & 1, wn = wave >> 1;
    const int mb = blockIdx.y, nb = blockIdx.x;

    // staging coords: per chunk c (0..3), wave covers 8 rows (1024 B of LDS)
    const int srow = lane >> 3;           // 0..7 within segment
    const int scol = (lane & 7) * 8;      // bf16 elements, 16 B per lane
    const long a_row0 = (long)mb * 128;
    const long b_row0 = (long)nb * 128;

    f32x4 acc[4][4] = {};

    for (int kt = 0; kt < K/64; ++kt) {
        const int k0 = kt * 64;
        __syncthreads();
        #pragma unroll
        for (int c = 0; c < 4; ++c) {
            const int seg = c*4 + wave;                    // 0..15 -> rows seg*8..
            const int row = seg*8 + srow;
            GLOAD_LDS16(A + (a_row0 + row)*K + k0 + scol, As + seg*512);
            GLOAD_LDS16(B + (b_row0 + row)*K + k0 + scol, Bs + seg*512);
        }
        __syncthreads();
        #pragma unroll
        for (int kk = 0; kk < 2; ++kk) {
            const int ko = kk*32 + quad*8;
            bf16x8 af[4], bfr[4];
            #pragma unroll
            for (int mt = 0; mt < 4; ++mt)
                af[mt] = *(const bf16x8*)(As + (wm*64 + mt*16 + c16)*64 + ko);
            #pragma unroll
            for (int nt = 0; nt < 4; ++nt)
                bfr[nt] = *(const bf16x8*)(Bs + (wn*64 + nt*16 + c16)*64 + ko);
            #pragma unroll
            for (int mt = 0; mt < 4; ++mt)
                #pragma unroll
                for (int nt = 0; nt < 4; ++nt)
                    acc[mt][nt] = __builtin_amdgcn_mfma_f32_16x16x32_bf16(
                        af[mt], bfr[nt], acc[mt][nt], 0, 0, 0);
        }
    }

    // epilogue: C/D layout col = c16 (+tile), row = quad*4 + r (+tile)
    #pragma unroll
    for (int nt = 0; nt < 4; ++nt) {
        const int col = nb*128 + wn*64 + nt*16 + c16;
        const float bv = bias[col];
        if constexpr (IS_QKV) {
            const int which = col / DIM;         // tile never straddles (1280%128==0)
            const int rr = col - which*DIM;
            const int h  = rr / HD;
            const int d  = rr - h*HD;
            bf16* dst = (which == 0) ? out0 : out1;
            #pragma unroll
            for (int mt = 0; mt < 4; ++mt) {
                #pragma unroll
                for (int r = 0; r < 4; ++r) {
                    const int row = mb*128 + wm*64 + mt*16 + quad*4 + r;
                    const int n = row >> 10, p = row & 1023;
                    const bf16 bf = (bf16)(acc[mt][nt][r] + bv);
                    if (which == 2)
                        out2[((long)((n*NHEADS + h)*HD + d))*MAXP + p] = bf;   // v^T
                    else
                        dst[((long)((n*NHEADS + h)*MAXP + p))*HD + d] = bf;    // q/k
                }
            }
        } else {
            #pragma unroll
            for (int mt = 0; mt < 4; ++mt) {
                #pragma unroll
                for (int r = 0; r < 4; ++r) {
                    const int row = mb*128 + wm*64 + mt*16 + quad*4 + r;
                    outf[(long)row*DIM + col] = acc[mt][nt][r] + bv;
                }
            }
        }
    }
}

// ---------------------------------------------------------------------------
// RoPE in-place on q,k (bf16 [n][h][p][80]); rope cache fp32 [n][p][160].
// One thread per (array, n, h, p, d<40) handles the (d, d+40) pair.
// 1/sqrt(80) folded into q.
// ---------------------------------------------------------------------------
__global__ __launch_bounds__(256)
void rope_kernel(bf16* __restrict__ qb, bf16* __restrict__ kb,
                 const float* __restrict__ rope)
{
    const int t = blockIdx.x * 256 + threadIdx.x;  // 2*16*16*1024*40 = 20971520
    const int d = t % 40;
    const int rest = t / 40;
    const int p = rest & 1023;
    const int r2 = rest >> 10;
    const int h = r2 & 15;
    const int r3 = r2 >> 4;
    const int n = r3 & 15;
    const int a = r3 >> 4;                          // 0 = q, 1 = k (block-uniform)
    bf16* arr = a ? kb : qb;
    const long base = ((long)((n*NHEADS + h)*MAXP + p))*HD;
    const float* rc = rope + ((long)(n*MAXP + p))*160;
    const float x1 = (float)arr[base + d];
    const float x2 = (float)arr[base + d + 40];
    float o1 = x1 * rc[d]      - x2 * rc[80 + d];        // cos[d],    sin[d]
    float o2 = x2 * rc[40 + d] + x1 * rc[120 + d];       // cos[d+40], sin[d+40]
    if (a == 0) { o1 *= 0.11180339887498949f; o2 *= 0.11180339887498949f; }
    arr[base + d]      = (bf16)o1;
    arr[base + d + 40] = (bf16)o2;
}

// ---------------------------------------------------------------------------
// Flash attention. Block = (q-tile of 64, h, n); 4 waves x 16 q-rows.
// Q/K global layout [n][h][p][80] bf16; LDS tiles padded to 96 cols (zeroed).
// K-tiles of 64 keys; S = Q K^T via MFMA (3 K-steps), online softmax,
// P -> LDS (C-layout -> A-layout), PV via MFMA (V staged transposed).
// ---------------------------------------------------------------------------
__global__ __launch_bounds__(256)
void attn_kernel(const bf16* __restrict__ qb, const bf16* __restrict__ kb,
                 const bf16* __restrict__ vt, const int* __restrict__ seq_lens,
                 bf16* __restrict__ outb)
{
    __shared__ __align__(16) bf16 Qs[64*104];    // stride 104 bf16 = 208 B
    __shared__ __align__(16) bf16 Ks[64*104];
    __shared__ __align__(16) bf16 Vts[80*72];    // V^T: [d][key], stride 144 B
    __shared__ __align__(16) bf16 Ps[4][16*72];  // per-wave P tile

    const int tid  = threadIdx.x;
    const int lane = tid & 63, wave = tid >> 6;
    const int quad = lane >> 4, c16 = lane & 15;
    const int qt = blockIdx.x, h = blockIdx.y, n = blockIdx.z;
    const int seqlen = seq_lens[n];

    const long qkbase = ((long)(n*NHEADS + h)) * MAXP * HD;
    const long vbase  = ((long)(n*NHEADS + h)) * HD * MAXP;

    const float4 zero4 = make_float4(0.f, 0.f, 0.f, 0.f);

    for (int i = tid; i < 768; i += 256) {       // 64 rows x 12 chunks of 16B
        int row = i / 12, c = i % 12;
        float4 v = (c < 10)
            ? *(const float4*)(qb + qkbase + (long)(qt*64 + row)*HD + c*8)
            : zero4;
        *(float4*)(Qs + row*104 + c*8) = v;
    }
    __syncthreads();
    bf16x8 aq[3];
    #pragma unroll
    for (int kc = 0; kc < 3; ++kc)
        aq[kc] = *(const bf16x8*)(Qs + (wave*16 + c16)*104 + kc*32 + quad*8);

    float mrow[4], lrow[4];
    #pragma unroll
    for (int r = 0; r < 4; ++r) { mrow[r] = -1e30f; lrow[r] = 0.0f; }
    f32x4 O[5] = {};

    const int nkt = (seqlen + 63) >> 6;
    for (int kt = 0; kt < nkt; ++kt) {
        __syncthreads();
        for (int i = tid; i < 768; i += 256) {
            int row = i / 12, c = i % 12;
            float4 v = (c < 10)
                ? *(const float4*)(kb + qkbase + (long)(kt*64 + row)*HD + c*8)
                : zero4;
            *(float4*)(Ks + row*104 + c*8) = v;
        }
        for (int i = tid; i < 640; i += 256) {   // 80 d-rows x 8 chunks
            int d = i >> 3, c = i & 7;
            *(float4*)(Vts + d*72 + c*8) =
                *(const float4*)(vt + vbase + (long)d*MAXP + kt*64 + c*8);
        }
        __syncthreads();

        f32x4 S[4] = {};
        #pragma unroll
        for (int kc = 0; kc < 3; ++kc) {
            const int ko = kc*32 + quad*8;
            #pragma unroll
            for (int nt = 0; nt < 4; ++nt) {
                bf16x8 bk = *(const bf16x8*)(Ks + (nt*16 + c16)*104 + ko);
                S[nt] = __builtin_amdgcn_mfma_f32_16x16x32_bf16(aq[kc], bk, S[nt], 0,0,0);
            }
        }
        #pragma unroll
        for (int nt = 0; nt < 4; ++nt) {
            const int key = kt*64 + nt*16 + c16;
            if (key >= seqlen) {
                #pragma unroll
                for (int r = 0; r < 4; ++r) S[nt][r] = -1e30f;
            }
        }
        float alpha[4];
        #pragma unroll
        for (int r = 0; r < 4; ++r) {
            float rm = fmaxf(fmaxf(S[0][r], S[1][r]), fmaxf(S[2][r], S[3][r]));
            rm = fmaxf(rm, __shfl_xor(rm, 1, 16));
            rm = fmaxf(rm, __shfl_xor(rm, 2, 16));
            rm = fmaxf(rm, __shfl_xor(rm, 4, 16));
            rm = fmaxf(rm, __shfl_xor(rm, 8, 16));
            const float nm = fmaxf(mrow[r], rm);
            alpha[r] = __expf(mrow[r] - nm);
            mrow[r] = nm;
            float rs = 0.0f;
            #pragma unroll
            for (int nt = 0; nt < 4; ++nt) {
                const float pv = __expf(S[nt][r] - nm);
                S[nt][r] = pv;
                rs += pv;
            }
            rs += __shfl_xor(rs, 1, 16);
            rs += __shfl_xor(rs, 2, 16);
            rs += __shfl_xor(rs, 4, 16);
            rs += __shfl_xor(rs, 8, 16);
            lrow[r] = lrow[r]*alpha[r] + rs;
        }
        #pragma unroll
        for (int dt = 0; dt < 5; ++dt)
            #pragma unroll
            for (int r = 0; r < 4; ++r)
                O[dt][r] *= alpha[r];
        #pragma unroll
        for (int nt = 0; nt < 4; ++nt)
            #pragma unroll
            for (int r = 0; r < 4; ++r)
                Ps[wave][(quad*4 + r)*72 + nt*16 + c16] = (bf16)S[nt][r];
        __syncthreads();
        #pragma unroll
        for (int kc = 0; kc < 2; ++kc) {
            bf16x8 ap = *(const bf16x8*)(Ps[wave] + c16*72 + kc*32 + quad*8);
            #pragma unroll
            for (int dt = 0; dt < 5; ++dt) {
                bf16x8 bv = *(const bf16x8*)(Vts + (dt*16 + c16)*72 + kc*32 + quad*8);
                O[dt] = __builtin_amdgcn_mfma_f32_16x16x32_bf16(ap, bv, O[dt], 0,0,0);
            }
        }
    }

    #pragma unroll
    for (int dt = 0; dt < 5; ++dt) {
        #pragma unroll
        for (int r = 0; r < 4; ++r) {
            const int p = qt*64 + wave*16 + quad*4 + r;
            const float v = O[dt][r] / lrow[r];
            outb[((long)(n*MAXP + p))*DIM + h*HD + dt*16 + c16] = (bf16)v;
        }
    }
}

// ---------------------------------------------------------------------------
// Buffer plan:
//   d_ws   : hidden_bf (42 MB) | wqkv_bf (9.8 MB) | wproj_bf (3.3 MB) = 52.5 MB
//   d_out  : q (42 MB bf16) | k (42 MB bf16)  — overwritten by proj fp32 at end
//   d_in[0]: vT (42 MB bf16) | attn_out (42 MB bf16) — hidden fp32 dead after cvt
// ---------------------------------------------------------------------------
extern "C" void kernel_launch(void* const* d_in, const int* in_sizes, int n_in,
                              void* d_out, int out_size, void* d_ws, size_t ws_size,
                              hipStream_t stream)
{
    const float* hidden = (const float*)d_in[0];
    const float* rope   = (const float*)d_in[1];
    const int*   seql   = (const int*)d_in[2];
    const float* wqkv   = (const float*)d_in[3];
    const float* bqkv   = (const float*)d_in[4];
    const float* wproj  = (const float*)d_in[5];
    const float* bproj  = (const float*)d_in[6];
    float* out = (float*)d_out;

    const size_t H_ELEMS  = (size_t)MTOT*DIM;          // 20,971,520
    const size_t WQ_ELEMS = (size_t)3*DIM*DIM;         //  4,915,200
    const size_t WP_ELEMS = (size_t)DIM*DIM;           //  1,638,400
    const size_t QK_ELEMS = (size_t)NV*NHEADS*MAXP*HD; // 20,971,520

    bf16* h_bf  = (bf16*)d_ws;
    bf16* wq_bf = h_bf  + H_ELEMS;
    bf16* wp_bf = wq_bf + WQ_ELEMS;

    bf16* q_b = (bf16*)d_out;
    bf16* k_b = q_b + QK_ELEMS;
    bf16* v_t = (bf16*)d_in[0];
    bf16* a_b = v_t + QK_ELEMS;

    cvt_bf16<<<(H_ELEMS/4 + 255)/256, 256, 0, stream>>>(hidden, h_bf, H_ELEMS/4);
    cvt_bf16<<<(WQ_ELEMS/4 + 255)/256, 256, 0, stream>>>(wqkv, wq_bf, WQ_ELEMS/4);
    cvt_bf16<<<(WP_ELEMS/4 + 255)/256, 256, 0, stream>>>(wproj, wp_bf, WP_ELEMS/4);

    gemm_nt_big<true><<<dim3(3*DIM/128, MTOT/128), 256, 0, stream>>>(
        h_bf, wq_bf, bqkv, q_b, k_b, v_t, nullptr);

    rope_kernel<<<(2*NV*NHEADS*MAXP*40)/256, 256, 0, stream>>>(q_b, k_b, rope);

    attn_kernel<<<dim3(MAXP/64, NHEADS, NV), 256, 0, stream>>>(
        q_b, k_b, v_t, seql, a_b);

    gemm_nt_big<false><<<dim3(DIM/128, MTOT/128), 256, 0, stream>>>(
        a_b, wp_bf, bproj, nullptr, nullptr, nullptr, out);
}

// Round 5
// 862.518 us; speedup vs baseline: 1.3172x; 1.0275x over previous
//
#include <hip/hip_runtime.h>
#include <stdint.h>

#define DIM     1280
#define NHEADS  16
#define HD      80
#define NV      16
#define MAXP    1024
#define MTOT    (NV*MAXP)   // 16384

typedef __bf16 bf16;
using bf16x8 = __attribute__((ext_vector_type(8))) __bf16;
using bf16x4 = __attribute__((ext_vector_type(4))) __bf16;
using f32x4  = __attribute__((ext_vector_type(4))) float;

#define GLOAD_LDS16(g, l)                                                     \
    __builtin_amdgcn_global_load_lds(                                         \
        (const __attribute__((address_space(1))) void*)(g),                   \
        (__attribute__((address_space(3))) void*)(l), 16, 0, 0)

// ---------------------------------------------------------------------------
// fp32 -> bf16 bulk convert (vectorized, n must be a multiple of 4)
// ---------------------------------------------------------------------------
__global__ __launch_bounds__(256)
void cvt_bf16(const float* __restrict__ src, bf16* __restrict__ dst, int n4)
{
    const int i = blockIdx.x * 256 + threadIdx.x;
    if (i < n4) {
        const float4 f = ((const float4*)src)[i];
        bf16x4 r;
        r[0] = (bf16)f.x; r[1] = (bf16)f.y; r[2] = (bf16)f.z; r[3] = (bf16)f.w;
        ((bf16x4*)dst)[i] = r;
    }
}

// ---------------------------------------------------------------------------
// m97-structure NT GEMM with XOR-swizzled LDS: C = A * B^T + bias.
// A, B bf16 row-major (K contiguous), K = 1280. BM=BN=128, BK=64.
// 256 threads = 4 waves in 2x2; each wave computes 64x64 = 4x4 MFMA 16x16.
// LDS layout: 16 segments of 8 rows; row r's 16B chunk j stored at slot
// j ^ (r&7)  -> fragment ds_read_b128 is 2-way (free) instead of 16-way.
// Staging via global_load_lds width=16 (dest = base + lane*16; the lane's
// GLOBAL source address is chosen to match the swizzle).
// IS_QKV: scatter into q [n][h][p][80], k [n][h][p][80], v^T [n][h][80][p].
// else  : fp32 row-major [M][DIM] output (proj).
// ---------------------------------------------------------------------------
template<bool IS_QKV>
__global__ __launch_bounds__(256)
void gemm_nt_big(const bf16* __restrict__ A, const bf16* __restrict__ B,
                 const float* __restrict__ bias,
                 bf16* __restrict__ out0, bf16* __restrict__ out1,
                 bf16* __restrict__ out2, float* __restrict__ outf)
{
    const int K = DIM;
    __shared__ __align__(16) bf16 As[128*64];
    __shared__ __align__(16) bf16 Bs[128*64];

    const int tid  = threadIdx.x;
    const int lane = tid & 63, wave = tid >> 6;
    const int quad = lane >> 4, c16 = lane & 15;
    const int wm = wave & 1, wn = wave >> 1;
    const int mb = blockIdx.y, nb = blockIdx.x;

    // staging: lane covers (segment row sr, slot) ; source chunk = slot ^ sr
    const int sr   = lane >> 3;              // 0..7
    const int slot = lane & 7;               // 0..7
    const int sc   = (slot ^ sr) * 8;        // swizzled source chunk (bf16 elems)
    const long a_row0 = (long)mb * 128;
    const long b_row0 = (long)nb * 128;

    const bf16* ga[4];
    const bf16* gb[4];
    #pragma unroll
    for (int c = 0; c < 4; ++c) {
        const int seg = c*4 + wave;
        const int row = seg*8 + sr;
        ga[c] = A + (a_row0 + row)*K + sc;
        gb[c] = B + (b_row0 + row)*K + sc;
    }

    f32x4 acc[4][4] = {};
    const int xr = c16 & 7;                  // fragment-read swizzle key

    for (int kt = 0; kt < K/64; ++kt) {
        const int k0 = kt * 64;
        __syncthreads();
        #pragma unroll
        for (int c = 0; c < 4; ++c) {
            const int seg = c*4 + wave;
            GLOAD_LDS16(ga[c] + k0, As + seg*512);
            GLOAD_LDS16(gb[c] + k0, Bs + seg*512);
        }
        __syncthreads();
        #pragma unroll
        for (int kk = 0; kk < 2; ++kk) {
            const int j  = kk*4 + quad;          // chunk index 0..7
            const int ko = ((j ^ xr) * 8);       // swizzled element offset
            bf16x8 af[4], bfr[4];
            #pragma unroll
            for (int mt = 0; mt < 4; ++mt)
                af[mt] = *(const bf16x8*)(As + (wm*64 + mt*16 + c16)*64 + ko);
            #pragma unroll
            for (int nt = 0; nt < 4; ++nt)
                bfr[nt] = *(const bf16x8*)(Bs + (wn*64 + nt*16 + c16)*64 + ko);
            #pragma unroll
            for (int mt = 0; mt < 4; ++mt)
                #pragma unroll
                for (int nt = 0; nt < 4; ++nt)
                    acc[mt][nt] = __builtin_amdgcn_mfma_f32_16x16x32_bf16(
                        af[mt], bfr[nt], acc[mt][nt], 0, 0, 0);
        }
    }

    // epilogue: C/D layout col = c16 (+tile), row = quad*4 + r (+tile)
    #pragma unroll
    for (int nt = 0; nt < 4; ++nt) {
        const int col = nb*128 + wn*64 + nt*16 + c16;
        const float bv = bias[col];
        if constexpr (IS_QKV) {
            const int which = col / DIM;         // tile never straddles (1280%128==0)
            const int rr = col - which*DIM;
            const int h  = rr / HD;
            const int d  = rr - h*HD;
            bf16* dst = (which == 0) ? out0 : out1;
            #pragma unroll
            for (int mt = 0; mt < 4; ++mt) {
                #pragma unroll
                for (int r = 0; r < 4; ++r) {
                    const int row = mb*128 + wm*64 + mt*16 + quad*4 + r;
                    const int n = row >> 10, p = row & 1023;
                    const bf16 bf = (bf16)(acc[mt][nt][r] + bv);
                    if (which == 2)
                        out2[((long)((n*NHEADS + h)*HD + d))*MAXP + p] = bf;   // v^T
                    else
                        dst[((long)((n*NHEADS + h)*MAXP + p))*HD + d] = bf;    // q/k
                }
            }
        } else {
            #pragma unroll
            for (int mt = 0; mt < 4; ++mt) {
                #pragma unroll
                for (int r = 0; r < 4; ++r) {
                    const int row = mb*128 + wm*64 + mt*16 + quad*4 + r;
                    outf[(long)row*DIM + col] = acc[mt][nt][r] + bv;
                }
            }
        }
    }
}

// ---------------------------------------------------------------------------
// RoPE in-place on q,k (bf16 [n][h][p][80]); rope cache fp32 [n][p][160].
// One thread per (array, n, h, p, d<40) handles the (d, d+40) pair.
// q additionally scaled by log2(e)/sqrt(80) (softmax runs in exp2 domain).
// ---------------------------------------------------------------------------
__global__ __launch_bounds__(256)
void rope_kernel(bf16* __restrict__ qb, bf16* __restrict__ kb,
                 const float* __restrict__ rope)
{
    const int t = blockIdx.x * 256 + threadIdx.x;  // 2*16*16*1024*40 = 20971520
    const int d = t % 40;
    const int rest = t / 40;
    const int p = rest & 1023;
    const int r2 = rest >> 10;
    const int h = r2 & 15;
    const int r3 = r2 >> 4;
    const int n = r3 & 15;
    const int a = r3 >> 4;                          // 0 = q, 1 = k (block-uniform)
    bf16* arr = a ? kb : qb;
    const long base = ((long)((n*NHEADS + h)*MAXP + p))*HD;
    const float* rc = rope + ((long)(n*MAXP + p))*160;
    const float x1 = (float)arr[base + d];
    const float x2 = (float)arr[base + d + 40];
    float o1 = x1 * rc[d]      - x2 * rc[80 + d];        // cos[d],    sin[d]
    float o2 = x2 * rc[40 + d] + x1 * rc[120 + d];       // cos[d+40], sin[d+40]
    // 1/sqrt(80) * log2(e)
    const float QS = 0.11180339887498949f * 1.4426950408889634f;
    if (a == 0) { o1 *= QS; o2 *= QS; }
    arr[base + d]      = (bf16)o1;
    arr[base + d + 40] = (bf16)o2;
}

// ---------------------------------------------------------------------------
// Flash attention (softmax in exp2 domain; log2e folded into q).
// Block = (q-tile of 64, h, n); 4 waves x 16 q-rows.
// ---------------------------------------------------------------------------
__global__ __launch_bounds__(256)
void attn_kernel(const bf16* __restrict__ qb, const bf16* __restrict__ kb,
                 const bf16* __restrict__ vt, const int* __restrict__ seq_lens,
                 bf16* __restrict__ outb)
{
    __shared__ __align__(16) bf16 Qs[64*104];    // stride 104 bf16 = 208 B
    __shared__ __align__(16) bf16 Ks[64*104];
    __shared__ __align__(16) bf16 Vts[80*72];    // V^T: [d][key], stride 144 B
    __shared__ __align__(16) bf16 Ps[4][16*72];  // per-wave P tile

    const int tid  = threadIdx.x;
    const int lane = tid & 63, wave = tid >> 6;
    const int quad = lane >> 4, c16 = lane & 15;
    const int qt = blockIdx.x, h = blockIdx.y, n = blockIdx.z;
    const int seqlen = seq_lens[n];

    const long qkbase = ((long)(n*NHEADS + h)) * MAXP * HD;
    const long vbase  = ((long)(n*NHEADS + h)) * HD * MAXP;

    const float4 zero4 = make_float4(0.f, 0.f, 0.f, 0.f);

    for (int i = tid; i < 768; i += 256) {       // 64 rows x 12 chunks of 16B
        int row = i / 12, c = i % 12;
        float4 v = (c < 10)
            ? *(const float4*)(qb + qkbase + (long)(qt*64 + row)*HD + c*8)
            : zero4;
        *(float4*)(Qs + row*104 + c*8) = v;
    }
    __syncthreads();
    bf16x8 aq[3];
    #pragma unroll
    for (int kc = 0; kc < 3; ++kc)
        aq[kc] = *(const bf16x8*)(Qs + (wave*16 + c16)*104 + kc*32 + quad*8);

    float mrow[4], lrow[4];
    #pragma unroll
    for (int r = 0; r < 4; ++r) { mrow[r] = -1e30f; lrow[r] = 0.0f; }
    f32x4 O[5] = {};

    const int nkt = (seqlen + 63) >> 6;
    for (int kt = 0; kt < nkt; ++kt) {
        __syncthreads();
        for (int i = tid; i < 768; i += 256) {
            int row = i / 12, c = i % 12;
            float4 v = (c < 10)
                ? *(const float4*)(kb + qkbase + (long)(kt*64 + row)*HD + c*8)
                : zero4;
            *(float4*)(Ks + row*104 + c*8) = v;
        }
        for (int i = tid; i < 640; i += 256) {   // 80 d-rows x 8 chunks
            int d = i >> 3, c = i & 7;
            *(float4*)(Vts + d*72 + c*8) =
                *(const float4*)(vt + vbase + (long)d*MAXP + kt*64 + c*8);
        }
        __syncthreads();

        f32x4 S[4] = {};
        #pragma unroll
        for (int kc = 0; kc < 3; ++kc) {
            const int ko = kc*32 + quad*8;
            #pragma unroll
            for (int nt = 0; nt < 4; ++nt) {
                bf16x8 bk = *(const bf16x8*)(Ks + (nt*16 + c16)*104 + ko);
                S[nt] = __builtin_amdgcn_mfma_f32_16x16x32_bf16(aq[kc], bk, S[nt], 0,0,0);
            }
        }
        #pragma unroll
        for (int nt = 0; nt < 4; ++nt) {
            const int key = kt*64 + nt*16 + c16;
            if (key >= seqlen) {
                #pragma unroll
                for (int r = 0; r < 4; ++r) S[nt][r] = -1e30f;
            }
        }
        float alpha[4];
        #pragma unroll
        for (int r = 0; r < 4; ++r) {
            float rm = fmaxf(fmaxf(S[0][r], S[1][r]), fmaxf(S[2][r], S[3][r]));
            rm = fmaxf(rm, __shfl_xor(rm, 1, 16));
            rm = fmaxf(rm, __shfl_xor(rm, 2, 16));
            rm = fmaxf(rm, __shfl_xor(rm, 4, 16));
            rm = fmaxf(rm, __shfl_xor(rm, 8, 16));
            const float nm = fmaxf(mrow[r], rm);
            alpha[r] = exp2f(mrow[r] - nm);
            mrow[r] = nm;
            float rs = 0.0f;
            #pragma unroll
            for (int nt = 0; nt < 4; ++nt) {
                const float pv = exp2f(S[nt][r] - nm);
                S[nt][r] = pv;
                rs += pv;
            }
            rs += __shfl_xor(rs, 1, 16);
            rs += __shfl_xor(rs, 2, 16);
            rs += __shfl_xor(rs, 4, 16);
            rs += __shfl_xor(rs, 8, 16);
            lrow[r] = lrow[r]*alpha[r] + rs;
        }
        #pragma unroll
        for (int dt = 0; dt < 5; ++dt)
            #pragma unroll
            for (int r = 0; r < 4; ++r)
                O[dt][r] *= alpha[r];
        #pragma unroll
        for (int nt = 0; nt < 4; ++nt)
            #pragma unroll
            for (int r = 0; r < 4; ++r)
                Ps[wave][(quad*4 + r)*72 + nt*16 + c16] = (bf16)S[nt][r];
        __syncthreads();
        #pragma unroll
        for (int kc = 0; kc < 2; ++kc) {
            bf16x8 ap = *(const bf16x8*)(Ps[wave] + c16*72 + kc*32 + quad*8);
            #pragma unroll
            for (int dt = 0; dt < 5; ++dt) {
                bf16x8 bv = *(const bf16x8*)(Vts + (dt*16 + c16)*72 + kc*32 + quad*8);
                O[dt] = __builtin_amdgcn_mfma_f32_16x16x32_bf16(ap, bv, O[dt], 0,0,0);
            }
        }
    }

    #pragma unroll
    for (int dt = 0; dt < 5; ++dt) {
        #pragma unroll
        for (int r = 0; r < 4; ++r) {
            const int p = qt*64 + wave*16 + quad*4 + r;
            const float v = O[dt][r] / lrow[r];
            outb[((long)(n*MAXP + p))*DIM + h*HD + dt*16 + c16] = (bf16)v;
        }
    }
}

// ---------------------------------------------------------------------------
// Buffer plan:
//   d_ws   : hidden_bf (42 MB) | wqkv_bf (9.8 MB) | wproj_bf (3.3 MB)
//   d_out  : q (42 MB bf16) | k (42 MB bf16)  — overwritten by proj fp32 at end
//   d_in[0]: vT (42 MB bf16) | attn_out (42 MB bf16) — hidden fp32 dead after cvt
// ---------------------------------------------------------------------------
extern "C" void kernel_launch(void* const* d_in, const int* in_sizes, int n_in,
                              void* d_out, int out_size, void* d_ws, size_t ws_size,
                              hipStream_t stream)
{
    const float* hidden = (const float*)d_in[0];
    const float* rope   = (const float*)d_in[1];
    const int*   seql   = (const int*)d_in[2];
    const float* wqkv   = (const float*)d_in[3];
    const float* bqkv   = (const float*)d_in[4];
    const float* wproj  = (const float*)d_in[5];
    const float* bproj  = (const float*)d_in[6];
    float* out = (float*)d_out;

    const size_t H_ELEMS  = (size_t)MTOT*DIM;          // 20,971,520
    const size_t WQ_ELEMS = (size_t)3*DIM*DIM;         //  4,915,200
    const size_t WP_ELEMS = (size_t)DIM*DIM;           //  1,638,400
    const size_t QK_ELEMS = (size_t)NV*NHEADS*MAXP*HD; // 20,971,520

    bf16* h_bf  = (bf16*)d_ws;
    bf16* wq_bf = h_bf  + H_ELEMS;
    bf16* wp_bf = wq_bf + WQ_ELEMS;

    bf16* q_b = (bf16*)d_out;
    bf16* k_b = q_b + QK_ELEMS;
    bf16* v_t = (bf16*)d_in[0];
    bf16* a_b = v_t + QK_ELEMS;

    cvt_bf16<<<(H_ELEMS/4 + 255)/256, 256, 0, stream>>>(hidden, h_bf, H_ELEMS/4);
    cvt_bf16<<<(WQ_ELEMS/4 + 255)/256, 256, 0, stream>>>(wqkv, wq_bf, WQ_ELEMS/4);
    cvt_bf16<<<(WP_ELEMS/4 + 255)/256, 256, 0, stream>>>(wproj, wp_bf, WP_ELEMS/4);

    gemm_nt_big<true><<<dim3(3*DIM/128, MTOT/128), 256, 0, stream>>>(
        h_bf, wq_bf, bqkv, q_b, k_b, v_t, nullptr);

    rope_kernel<<<(2*NV*NHEADS*MAXP*40)/256, 256, 0, stream>>>(q_b, k_b, rope);

    attn_kernel<<<dim3(MAXP/64, NHEADS, NV), 256, 0, stream>>>(
        q_b, k_b, v_t, seql, a_b);

    gemm_nt_big<false><<<dim3(DIM/128, MTOT/128), 256, 0, stream>>>(
        a_b, wp_bf, bproj, nullptr, nullptr, nullptr, out);
}